// Round 4
// baseline (2719.525 us; speedup 1.0000x reference)
//
#include <hip/hip_runtime.h>
#include <math.h>

// CrossAttentionBlock on MI355X — round 4:
//  * flash-fused attention (QK^T + exact softmax + PV in one kernel; S/Pbf
//    HBM round-trips eliminated; attn f32 written once as required output)
//  * qkv_gemm V-epilogue LDS transpose -> coalesced Vt stores
//  * final_up 2px/thread float2
//
// Workspace (bytes):
//   [0..12582912)            Aimg bf16 [8192][768]
//   [12582912..25165824)     Actx bf16
//   [25165824..50331648)     XC  bf16 [16384][768]
//   [50331648..75497472)     Qm  bf16 [64][1024][192]
//   [75497472..100663296)    Km
//   [134217728..159383552)   Vt  bf16 [64][192][1024]
//   [159383552..184549376)   O2  bf16 [16384][768]
//   [184549376..209715200)   P   f32  [16384][384]
//   [209715200..)            weight conversions (Wpat, Wctx, Wqt, Wpt)

namespace {

typedef unsigned short u16;
typedef __attribute__((ext_vector_type(8))) __bf16 bf16x8;
typedef __attribute__((ext_vector_type(4))) float f32x4;

constexpr float SCALE = 0.10206207261596577f;  // 96^-0.5 (reference quirk)

__device__ __forceinline__ u16 f2bf(float x) {
  unsigned u = __float_as_uint(x);
  return (u16)((u + 0x7FFFu + ((u >> 16) & 1u)) >> 16);
}

// ---- generic MFMA core (m97 structure) ------------------------------------
template <int BM, int BN>
__device__ __forceinline__ void mfma_core(const u16* __restrict__ A, int lda, int m0,
                                          const u16* __restrict__ B, int ldb, int n0,
                                          int K, u16* As, u16* Bs,
                                          f32x4 (&acc)[BM / 32][BN / 32]) {
  const int tid = threadIdx.x;
  const int lane = tid & 63, wid = tid >> 6;
  const int wr = wid >> 1, wc = wid & 1;
  const int fr = lane & 15, ks = lane >> 4;
  const int srow = lane >> 2, sslot = lane & 3;
  for (int kc = 0; kc < K; kc += 32) {
#pragma unroll
    for (int t = 0; t < BM / 64; ++t) {
      const int rb = (wid * (BM / 64) + t) * 16;
      const u16* src = A + (size_t)(m0 + rb + srow) * lda + kc + sslot * 8;
      __builtin_amdgcn_global_load_lds((const __attribute__((address_space(1))) void*)src,
                                       (__attribute__((address_space(3))) void*)(As + rb * 32),
                                       16, 0, 0);
    }
#pragma unroll
    for (int t = 0; t < BN / 64; ++t) {
      const int rb = (wid * (BN / 64) + t) * 16;
      const u16* src = B + (size_t)(n0 + rb + srow) * ldb + kc + sslot * 8;
      __builtin_amdgcn_global_load_lds((const __attribute__((address_space(1))) void*)src,
                                       (__attribute__((address_space(3))) void*)(Bs + rb * 32),
                                       16, 0, 0);
    }
    __syncthreads();
    bf16x8 a[BM / 32], b[BN / 32];
#pragma unroll
    for (int mi = 0; mi < BM / 32; ++mi)
      a[mi] = *(const bf16x8*)(As + (wr * (BM / 2) + mi * 16 + fr) * 32 + ks * 8);
#pragma unroll
    for (int ni = 0; ni < BN / 32; ++ni)
      b[ni] = *(const bf16x8*)(Bs + (wc * (BN / 2) + ni * 16 + fr) * 32 + ks * 8);
#pragma unroll
    for (int mi = 0; mi < BM / 32; ++mi)
#pragma unroll
      for (int ni = 0; ni < BN / 32; ++ni)
        acc[mi][ni] = __builtin_amdgcn_mfma_f32_16x16x32_bf16(a[mi], b[ni], acc[mi][ni], 0, 0, 0);
    __syncthreads();
  }
}

// ---- conversions ----------------------------------------------------------

__global__ void cvt_bf16(const float* __restrict__ in, u16* __restrict__ out) {
  const int i = blockIdx.x * 256 + threadIdx.x;
  const float4 v = ((const float4*)in)[i];
  ((ushort4*)out)[i] = make_ushort4(f2bf(v.x), f2bf(v.y), f2bf(v.z), f2bf(v.w));
}

__global__ void cvt_t(const float* __restrict__ in, u16* __restrict__ out, int N, int K) {
  __shared__ float t[32][33];
  const int tx = threadIdx.x, ty = threadIdx.y;
  const int bn = blockIdx.x * 32, bk = blockIdx.y * 32;
#pragma unroll
  for (int i = 0; i < 4; ++i) t[ty * 4 + i][tx] = in[(size_t)(bk + ty * 4 + i) * N + bn + tx];
  __syncthreads();
#pragma unroll
  for (int i = 0; i < 4; ++i)
    out[(size_t)(bn + ty * 4 + i) * K + bk + tx] = f2bf(t[tx][ty * 4 + i]);
}

// ---- im2col (bf16 out) ----------------------------------------------------

__global__ void im2col_img(const float* __restrict__ img, u16* __restrict__ A) {
  const int t = threadIdx.x;   // 0..191
  const int row = blockIdx.x;  // b*1024 + n
  const int k4 = t * 4;
  const int c = k4 >> 8, rem = k4 & 255, i = rem >> 4, j = rem & 15;
  const int b = row >> 10, n = row & 1023;
  const int hp = n >> 5, wp = n & 31;
  const float4 v = *(const float4*)(img + ((size_t)(b * 3 + c) * 512 + hp * 16 + i) * 512 + wp * 16 + j);
  *(ushort4*)(A + (size_t)row * 768 + k4) = make_ushort4(f2bf(v.x), f2bf(v.y), f2bf(v.z), f2bf(v.w));
}

__global__ void im2col_ctx(const float* __restrict__ ctx, u16* __restrict__ A) {
  const int t = threadIdx.x;
  const int row = blockIdx.x;
  const int k4 = t * 4;
  const int c = k4 >> 8, rem = k4 & 255, i = rem >> 4, j = rem & 15;
  const int b = row >> 10, n = row & 1023;
  const int hp = n >> 5, wp = n & 31;
  const int y = hp * 16 + i, x = wp * 16 + j;
  const float* base = ctx + ((size_t)(b * 3 + c) * 1024 + 2 * y) * 1024 + 2 * x;
  const float4 r0a = *(const float4*)(base);
  const float4 r0b = *(const float4*)(base + 4);
  const float4 r1a = *(const float4*)(base + 1024);
  const float4 r1b = *(const float4*)(base + 1028);
  *(ushort4*)(A + (size_t)row * 768 + k4) = make_ushort4(
      f2bf(fmaxf(fmaxf(r0a.x, r0a.y), fmaxf(r1a.x, r1a.y))),
      f2bf(fmaxf(fmaxf(r0a.z, r0a.w), fmaxf(r1a.z, r1a.w))),
      f2bf(fmaxf(fmaxf(r0b.x, r0b.y), fmaxf(r1b.x, r1b.y))),
      f2bf(fmaxf(fmaxf(r0b.z, r0b.w), fmaxf(r1b.z, r1b.w))));
}

// ---- patch embed GEMM -----------------------------------------------------

__global__ __launch_bounds__(256) void patch_gemm(
    const u16* __restrict__ A, const u16* __restrict__ W,
    const float* __restrict__ bias, const float* __restrict__ pos,
    u16* __restrict__ XC, int branch) {
  __shared__ u16 As[128 * 32], Bs[128 * 32];
  f32x4 acc[4][4];
#pragma unroll
  for (int mi = 0; mi < 4; ++mi)
#pragma unroll
    for (int ni = 0; ni < 4; ++ni) acc[mi][ni] = f32x4{0.f, 0.f, 0.f, 0.f};
  const int m0 = blockIdx.y * 128, n0 = blockIdx.x * 128;
  mfma_core<128, 128>(A, 768, m0, W, 768, n0, 768, As, Bs, acc);
  const int tid = threadIdx.x, lane = tid & 63, wid = tid >> 6;
  const int wr = wid >> 1, wc = wid & 1, fr = lane & 15, ks = lane >> 4;
#pragma unroll
  for (int mi = 0; mi < 4; ++mi)
#pragma unroll
    for (int j = 0; j < 4; ++j) {
      const int row = m0 + wr * 64 + mi * 16 + ks * 4 + j;
      const int b = row >> 10, n = row & 1023;
      u16* dst = XC + ((size_t)b * 2048 + branch * 1024 + n) * 768;
#pragma unroll
      for (int ni = 0; ni < 4; ++ni) {
        const int col = n0 + wc * 64 + ni * 16 + fr;
        dst[col] = f2bf(acc[mi][ni][j] + bias[col] + pos[(size_t)n * 768 + col]);
      }
    }
}

// ---- qkv GEMM with Q/K direct scatter + V LDS-transposed coalesced store --
__global__ __launch_bounds__(256) void qkv_gemm(
    const u16* __restrict__ XC, const u16* __restrict__ Wt,
    u16* __restrict__ Qm, u16* __restrict__ Km, u16* __restrict__ Vt) {
  __shared__ u16 As[128 * 32], Bs[128 * 32];
  __shared__ u16 vtile[128][72];  // [dloc][nloc(+pad)] 18 KB
  f32x4 acc[4][4];
#pragma unroll
  for (int mi = 0; mi < 4; ++mi)
#pragma unroll
    for (int ni = 0; ni < 4; ++ni) acc[mi][ni] = f32x4{0.f, 0.f, 0.f, 0.f};
  const int m0 = blockIdx.y * 128, n0 = blockIdx.x * 128;
  mfma_core<128, 128>(XC, 768, m0, Wt, 768, n0, 768, As, Bs, acc);
  const int tid = threadIdx.x, lane = tid & 63, wid = tid >> 6;
  const int wr = wid >> 1, wc = wid & 1, fr = lane & 15, ks = lane >> 4;
  const bool hasV = (n0 >= 768);          // odd rows of this block are V
  const int bq = m0 >> 11;                // batch (blocks never straddle)
  const int nbase = (m0 & 2047) >> 1;
#pragma unroll
  for (int mi = 0; mi < 4; ++mi)
#pragma unroll
    for (int j = 0; j < 4; ++j) {
      const int row = m0 + wr * 64 + mi * 16 + ks * 4 + j;
      const int rl = row & 2047;
      const int n = rl >> 1, odd = rl & 1;
#pragma unroll
      for (int ni = 0; ni < 4; ++ni) {
        const int col = n0 + wc * 64 + ni * 16 + fr;
        const u16 v = f2bf(acc[mi][ni][j]);
        if (!odd) {
          if (col < 1536) {
            const int h = col / 192, d = col - h * 192;
            Qm[((size_t)(bq * 8 + h) * 1024 + n) * 192 + d] = v;
          } else {
            const int c2 = col - 1536, h = c2 / 192, d = c2 - h * 192;
            Km[((size_t)(bq * 8 + h) * 1024 + n) * 192 + d] = v;
          }
        } else if (hasV) {
          vtile[col - n0][n - nbase] = v;
        } else {  // odd, col < 768 -> K heads 4..7
          const int h = col / 192, d = col - h * 192;
          Km[((size_t)(bq * 8 + 4 + h) * 1024 + n) * 192 + d] = v;
        }
      }
    }
  if (hasV) {
    __syncthreads();
#pragma unroll
    for (int t = 0; t < 4; ++t) {
      const int slot = t * 256 + tid;     // 1024 slots of 16B
      const int dloc = slot >> 3, m = slot & 7;
      const int dglob = n0 - 768 + dloc;
      const int h = dglob / 192, dd = dglob - h * 192;
      *(uint4*)(Vt + ((size_t)(bq * 8 + h) * 192 + dd) * 1024 + nbase + m * 8) =
          *(const uint4*)(&vtile[dloc][m * 8]);
    }
  }
}

// ---- flash-fused attention: QK^T + exact softmax + PV ---------------------
// Block: 16 query rows of one (b,h); 256 threads = 4 waves (wave = col group).
// acc[8 nc][2 ti] = 16x1024 scores in regs. K/V streamed via LDS in
// [kc][row][32] layout (64B row stride: bank-optimal for ds_read_b128).
__global__ __launch_bounds__(256) void attn_fused(
    const u16* __restrict__ Qm, const u16* __restrict__ Km,
    const u16* __restrict__ Vt, float* __restrict__ outA, u16* __restrict__ O2) {
  const int rc = blockIdx.x;          // row chunk 0..63
  const int bh = blockIdx.y;          // 0..63
  const int b = bh >> 3, h = bh & 7;
  const int tid = threadIdx.x, lane = tid & 63, wid = tid >> 6;
  const int fr = lane & 15, ks = lane >> 4;

  const u16* Q = Qm + (size_t)bh * 196608;   // [1024][192]
  const u16* K = Km + (size_t)bh * 196608;
  const u16* V = Vt + (size_t)bh * 196608;   // [192][1024]
  float* Sb = outA + ((size_t)bh << 20);

  __shared__ u16 KV[12288];                  // 24 KB: [3][128][32] / [2][192][32]
  __shared__ u16 P_lds[32 * 16 * 32];        // 32 KB: [kc2 32][row 16][32]
  __shared__ float red[16][4];

  // Q fragments for this block's 16 rows (from global; 6 K-steps of 32)
  bf16x8 qa[6];
  {
    const u16* qrow = Q + (size_t)(rc * 16 + fr) * 192 + ks * 8;
#pragma unroll
    for (int kc = 0; kc < 6; ++kc) qa[kc] = *(const bf16x8*)(qrow + kc * 32);
  }

  f32x4 acc[8][2];
#pragma unroll
  for (int nc = 0; nc < 8; ++nc)
#pragma unroll
    for (int ti = 0; ti < 2; ++ti) acc[nc][ti] = f32x4{0.f, 0.f, 0.f, 0.f};

  // ---- phase 1: S = Q K^T (cols = K rows), staged [3][128][32] per half ---
  for (int nc = 0; nc < 8; ++nc) {
#pragma unroll 1
    for (int half = 0; half < 2; ++half) {
#pragma unroll
      for (int t = 0; t < 6; ++t) {
        const int kcl = t >> 1;
        const int r = ((t & 1) << 8) + tid;
        const int krow = r >> 2, m = r & 3;
        const u16* src = K + (size_t)(nc * 128 + krow) * 192 + half * 96 + kcl * 32 + m * 8;
        __builtin_amdgcn_global_load_lds((const __attribute__((address_space(1))) void*)src,
                                         (__attribute__((address_space(3))) void*)(KV + (t * 256 + tid) * 8),
                                         16, 0, 0);
      }
      __syncthreads();
#pragma unroll
      for (int kcl = 0; kcl < 3; ++kcl) {
        const bf16x8 aq = qa[half * 3 + kcl];
#pragma unroll
        for (int ti = 0; ti < 2; ++ti) {
          const bf16x8 bk = *(const bf16x8*)(KV + (kcl * 128 + wid * 32 + ti * 16 + fr) * 32 + ks * 8);
          acc[nc][ti] = __builtin_amdgcn_mfma_f32_16x16x32_bf16(aq, bk, acc[nc][ti], 0, 0, 0);
        }
      }
      __syncthreads();
    }
  }

  // ---- phase 2: exact softmax over the 1024-wide rows ---------------------
  float mj[4];
#pragma unroll
  for (int j = 0; j < 4; ++j) mj[j] = -3.4e38f;
#pragma unroll
  for (int nc = 0; nc < 8; ++nc)
#pragma unroll
    for (int ti = 0; ti < 2; ++ti)
#pragma unroll
      for (int j = 0; j < 4; ++j) mj[j] = fmaxf(mj[j], acc[nc][ti][j]);
#pragma unroll
  for (int w = 1; w <= 8; w <<= 1)
#pragma unroll
    for (int j = 0; j < 4; ++j) mj[j] = fmaxf(mj[j], __shfl_xor(mj[j], w));
  if (fr == 0) {
#pragma unroll
    for (int j = 0; j < 4; ++j) red[ks * 4 + j][wid] = mj[j];
  }
  __syncthreads();
  float rm[4];
#pragma unroll
  for (int j = 0; j < 4; ++j) {
    const float4 q = *(const float4*)red[ks * 4 + j];
    rm[j] = fmaxf(fmaxf(q.x, q.y), fmaxf(q.z, q.w));
  }
  __syncthreads();
  float sj[4] = {0.f, 0.f, 0.f, 0.f};
#pragma unroll
  for (int nc = 0; nc < 8; ++nc)
#pragma unroll
    for (int ti = 0; ti < 2; ++ti)
#pragma unroll
      for (int j = 0; j < 4; ++j) {
        const float p = expf((acc[nc][ti][j] - rm[j]) * SCALE);
        acc[nc][ti][j] = p;
        sj[j] += p;
      }
#pragma unroll
  for (int w = 1; w <= 8; w <<= 1)
#pragma unroll
    for (int j = 0; j < 4; ++j) sj[j] += __shfl_xor(sj[j], w);
  if (fr == 0) {
#pragma unroll
    for (int j = 0; j < 4; ++j) red[ks * 4 + j][wid] = sj[j];
  }
  __syncthreads();
  float inv[4];
#pragma unroll
  for (int j = 0; j < 4; ++j) {
    const float4 q = *(const float4*)red[ks * 4 + j];
    inv[j] = 1.0f / (q.x + q.y + q.z + q.w);
  }
  // write normalized attn (f32 output) + P_lds (bf16, PV A-operand layout)
#pragma unroll
  for (int nc = 0; nc < 8; ++nc)
#pragma unroll
    for (int ti = 0; ti < 2; ++ti)
#pragma unroll
      for (int j = 0; j < 4; ++j) {
        const float pn = acc[nc][ti][j] * inv[j];
        const int row = ks * 4 + j;
        const int col = nc * 128 + wid * 32 + ti * 16 + fr;
        Sb[(size_t)(rc * 16 + row) * 1024 + col] = pn;
        P_lds[(((col >> 5) * 16) + row) * 32 + (col & 31)] = f2bf(pn);
      }
  __syncthreads();

  // ---- phase 3: O = P V, V staged [2][192][32] per 64-k chunk -------------
  f32x4 oacc[3];
#pragma unroll
  for (int ti = 0; ti < 3; ++ti) oacc[ti] = f32x4{0.f, 0.f, 0.f, 0.f};
#pragma unroll 1
  for (int kp = 0; kp < 16; ++kp) {
#pragma unroll
    for (int t = 0; t < 6; ++t) {
      const int kcl = t / 3;
      const int r = (t - kcl * 3) * 256 + tid;
      const int d = r >> 2, m = r & 3;
      const u16* src = V + (size_t)d * 1024 + kp * 64 + kcl * 32 + m * 8;
      __builtin_amdgcn_global_load_lds((const __attribute__((address_space(1))) void*)src,
                                       (__attribute__((address_space(3))) void*)(KV + (t * 256 + tid) * 8),
                                       16, 0, 0);
    }
    __syncthreads();
#pragma unroll
    for (int kcl = 0; kcl < 2; ++kcl) {
      const bf16x8 pa = *(const bf16x8*)(P_lds + ((kp * 2 + kcl) * 16 + fr) * 32 + ks * 8);
#pragma unroll
      for (int ti = 0; ti < 3; ++ti) {
        const bf16x8 bv = *(const bf16x8*)(KV + (kcl * 192 + wid * 48 + ti * 16 + fr) * 32 + ks * 8);
        oacc[ti] = __builtin_amdgcn_mfma_f32_16x16x32_bf16(pa, bv, oacc[ti], 0, 0, 0);
      }
    }
    __syncthreads();
  }

  // epilogue: inverse-quirk scatter into O2
#pragma unroll
  for (int ti = 0; ti < 3; ++ti)
#pragma unroll
    for (int j = 0; j < 4; ++j) {
      const int n = rc * 16 + ks * 4 + j;
      const int r2 = 2 * n + (h >> 2);
      const int d = wid * 48 + ti * 16 + fr;
      O2[((size_t)b * 2048 + r2) * 768 + (h & 3) * 192 + d] = f2bf(oacc[ti][j]);
    }
}

// ---- proj GEMM + bias -----------------------------------------------------
__global__ __launch_bounds__(256) void proj_gemm(
    const u16* __restrict__ O2, const u16* __restrict__ Wt,
    const float* __restrict__ bias, float* __restrict__ P) {
  __shared__ u16 As[128 * 32], Bs[128 * 32];
  f32x4 acc[4][4];
#pragma unroll
  for (int mi = 0; mi < 4; ++mi)
#pragma unroll
    for (int ni = 0; ni < 4; ++ni) acc[mi][ni] = f32x4{0.f, 0.f, 0.f, 0.f};
  const int m0 = blockIdx.y * 128, n0 = blockIdx.x * 128;
  mfma_core<128, 128>(O2, 768, m0, Wt, 768, n0, 768, As, Bs, acc);
  const int tid = threadIdx.x, lane = tid & 63, wid = tid >> 6;
  const int wr = wid >> 1, wc = wid & 1, fr = lane & 15, ks = lane >> 4;
#pragma unroll
  for (int mi = 0; mi < 4; ++mi)
#pragma unroll
    for (int j = 0; j < 4; ++j) {
      const int row = m0 + wr * 64 + mi * 16 + ks * 4 + j;
#pragma unroll
      for (int ni = 0; ni < 4; ++ni) {
        const int col = n0 + wc * 64 + ni * 16 + fr;
        P[(size_t)row * 384 + col] = acc[mi][ni][j] + bias[col];
      }
    }
}

// ---- fused 1x1 conv + bilinear x2 (align_corners) + sigmoid + gate --------
__global__ __launch_bounds__(256) void final_up(
    const float* __restrict__ P, const float* __restrict__ ctx,
    const float* __restrict__ up_w, const float* __restrict__ up_b,
    float* __restrict__ outY) {
  const size_t idx = (size_t)blockIdx.x * 256 + threadIdx.x;  // 8*1024*512
  const int owp = (int)(idx & 511);
  const int oh = (int)((idx >> 9) & 1023);
  const int b = (int)(idx >> 19);
  const float rr = 511.0f / 1023.0f;
  const float fy = oh * rr;
  const int y0 = (int)fy;
  const int y1 = y0 < 511 ? y0 + 1 : 511;
  const float wy = fy - (float)y0;
  const float* Pb = P + (size_t)b * 786432;
  float v[2][3];
#pragma unroll
  for (int px = 0; px < 2; ++px) {
    const int ow = owp * 2 + px;
    const float fx = ow * rr;
    const int x0 = (int)fx;
    const int x1 = x0 < 511 ? x0 + 1 : 511;
    const float wx = fx - (float)x0;
#pragma unroll
    for (int ci = 0; ci < 3; ++ci) {
      const float* pc = Pb + ci * 262144;
      const float a00 = pc[y0 * 512 + x0], a01 = pc[y0 * 512 + x1];
      const float a10 = pc[y1 * 512 + x0], a11 = pc[y1 * 512 + x1];
      v[px][ci] = (a00 * (1.f - wx) + a01 * wx) * (1.f - wy) +
                  (a10 * (1.f - wx) + a11 * wx) * wy;
    }
  }
#pragma unroll
  for (int co = 0; co < 3; ++co) {
    const size_t o = (((size_t)b * 3 + co) << 20) + ((size_t)oh << 10) + owp * 2;
    const float2 c2 = *(const float2*)(ctx + o);
    float2 res;
#pragma unroll
    for (int px = 0; px < 2; ++px) {
      float u = up_b[co];
#pragma unroll
      for (int ci = 0; ci < 3; ++ci) u = fmaf(up_w[co * 3 + ci], v[px][ci], u);
      const float sg = 1.0f / (1.0f + expf(-u));
      if (px == 0) res.x = sg * c2.x; else res.y = sg * c2.y;
    }
    *(float2*)(outY + o) = res;
  }
}

}  // namespace

extern "C" void kernel_launch(void* const* d_in, const int* in_sizes, int n_in,
                              void* d_out, int out_size, void* d_ws, size_t ws_size,
                              hipStream_t stream) {
  const float* img = (const float*)d_in[0];
  const float* ctx = (const float*)d_in[1];
  const float* patch_w = (const float*)d_in[2];
  const float* patch_b = (const float*)d_in[3];
  const float* pos1 = (const float*)d_in[4];
  const float* ctx_w = (const float*)d_in[5];
  const float* ctx_b = (const float*)d_in[6];
  const float* pos2 = (const float*)d_in[7];
  const float* qkv_w = (const float*)d_in[8];
  const float* proj_w = (const float*)d_in[9];
  const float* proj_b = (const float*)d_in[10];
  const float* up_w = (const float*)d_in[11];
  const float* up_b = (const float*)d_in[12];

  char* wsb = (char*)d_ws;
  u16* Aimg = (u16*)(wsb);
  u16* Actx = (u16*)(wsb + 12582912);
  u16* XC   = (u16*)(wsb + 25165824);
  u16* Qm   = (u16*)(wsb + 50331648);
  u16* Km   = (u16*)(wsb + 75497472);
  u16* Vt   = (u16*)(wsb + 134217728);
  u16* O2   = (u16*)(wsb + 159383552);
  float* P  = (float*)(wsb + 184549376);
  u16* Wpat = (u16*)(wsb + 209715200);
  u16* Wctx = (u16*)(wsb + 210894848);
  u16* Wqt  = (u16*)(wsb + 212074496);
  u16* Wpt  = (u16*)(wsb + 215613440);

  float* outY = (float*)d_out;             // (8,3,1024,1024)
  float* outA = (float*)d_out + 25165824;  // (8,8,1024,1024)

  cvt_bf16<<<576, 256, 0, stream>>>(patch_w, Wpat);
  cvt_bf16<<<576, 256, 0, stream>>>(ctx_w, Wctx);
  cvt_t<<<dim3(72, 24), dim3(32, 8), 0, stream>>>(qkv_w, Wqt, 2304, 768);
  cvt_t<<<dim3(12, 24), dim3(32, 8), 0, stream>>>(proj_w, Wpt, 384, 768);
  im2col_img<<<8192, 192, 0, stream>>>(img, Aimg);
  im2col_ctx<<<8192, 192, 0, stream>>>(ctx, Actx);
  patch_gemm<<<dim3(6, 64), 256, 0, stream>>>(Aimg, Wpat, patch_b, pos1, XC, 0);
  patch_gemm<<<dim3(6, 64), 256, 0, stream>>>(Actx, Wctx, ctx_b, pos2, XC, 1);
  qkv_gemm<<<dim3(18, 128), 256, 0, stream>>>(XC, Wqt, Qm, Km, Vt);
  attn_fused<<<dim3(64, 64), 256, 0, stream>>>(Qm, Km, Vt, outA, O2);
  proj_gemm<<<dim3(3, 128), 256, 0, stream>>>(O2, Wpt, proj_b, P);
  final_up<<<16384, 256, 0, stream>>>(P, ctx, up_w, up_b, outY);
}